// Round 1
// baseline (25.959 us; speedup 1.0000x reference)
//
#include <hip/hip_runtime.h>

// ColorReducer: for each pixel (r,g,b), find argmin_k ||pix - palette[k]||^2
// using the EXACT reference formula d2 = (x2 - 2*cross) + p2 with
// left-to-right 3-term sums and no FMA contraction (bit-exact argmin vs
// numpy reference -> no label flips near ties). Output = palette[label],
// laid out (B, 3, H, W).

constexpr int HW    = 512 * 512;   // 262144 = 2^18
constexpr int BATCH = 16;
constexpr int KCOL  = 16;
constexpr long NPIX = (long)BATCH * HW;   // 4,194,304 pixels
constexpr int PIX_PER_THREAD = 4;

__global__ __launch_bounds__(256) void color_reduce_kernel(
    const float* __restrict__ x,       // (B, 3, H, W)
    const float* __restrict__ pal,     // (16, 3)
    float* __restrict__ out)           // (B, 3, H, W)
{
    __shared__ float spal[KCOL * 3];
    if (threadIdx.x < KCOL * 3) spal[threadIdx.x] = pal[threadIdx.x];
    __syncthreads();

    const long t  = (long)blockIdx.x * blockDim.x + threadIdx.x;
    const long n0 = t * PIX_PER_THREAD;
    if (n0 >= NPIX) return;

    const int b   = (int)(n0 >> 18);        // n0 / HW
    const int pix = (int)(n0 & (HW - 1));   // n0 % HW

    const float* base = x + (size_t)b * 3 * HW + pix;
    const float4 rv = *reinterpret_cast<const float4*>(base);
    const float4 gv = *reinterpret_cast<const float4*>(base + HW);
    const float4 bv = *reinterpret_cast<const float4*>(base + 2 * HW);

    float r[4]  = {rv.x, rv.y, rv.z, rv.w};
    float g[4]  = {gv.x, gv.y, gv.z, gv.w};
    float bl[4] = {bv.x, bv.y, bv.z, bv.w};

    float x2[4], best[4];
    int bestk[4];
#pragma unroll
    for (int i = 0; i < 4; ++i) {
        // x2 = ((r*r + g*g) + b*b), strict rounding, no contraction
        x2[i] = __fadd_rn(__fadd_rn(__fmul_rn(r[i], r[i]),
                                    __fmul_rn(g[i], g[i])),
                          __fmul_rn(bl[i], bl[i]));
        best[i]  = 3.4e38f;
        bestk[i] = 0;
    }

#pragma unroll
    for (int k = 0; k < KCOL; ++k) {
        // Uniform palette reads -> scalarize to s_load / SGPRs
        const float pr = pal[3 * k + 0];
        const float pg = pal[3 * k + 1];
        const float pb = pal[3 * k + 2];
        const float p2 = __fadd_rn(__fadd_rn(__fmul_rn(pr, pr),
                                             __fmul_rn(pg, pg)),
                                   __fmul_rn(pb, pb));
#pragma unroll
        for (int i = 0; i < 4; ++i) {
            const float cross = __fadd_rn(__fadd_rn(__fmul_rn(r[i], pr),
                                                    __fmul_rn(g[i], pg)),
                                          __fmul_rn(bl[i], pb));
            // d2 = (x2 - 2*cross) + p2  — exact reference evaluation order
            const float d2 = __fadd_rn(__fsub_rn(x2[i], __fmul_rn(2.0f, cross)),
                                       p2);
            if (d2 < best[i]) {   // strict < : first-index tie-break (np.argmin)
                best[i]  = d2;
                bestk[i] = k;
            }
        }
    }

    // Gather winning colors (divergent index -> LDS palette)
    float orr[4], ogg[4], obb[4];
#pragma unroll
    for (int i = 0; i < 4; ++i) {
        orr[i] = spal[3 * bestk[i] + 0];
        ogg[i] = spal[3 * bestk[i] + 1];
        obb[i] = spal[3 * bestk[i] + 2];
    }

    float* ob = out + (size_t)b * 3 * HW + pix;
    *reinterpret_cast<float4*>(ob)          = make_float4(orr[0], orr[1], orr[2], orr[3]);
    *reinterpret_cast<float4*>(ob + HW)     = make_float4(ogg[0], ogg[1], ogg[2], ogg[3]);
    *reinterpret_cast<float4*>(ob + 2 * HW) = make_float4(obb[0], obb[1], obb[2], obb[3]);
}

extern "C" void kernel_launch(void* const* d_in, const int* in_sizes, int n_in,
                              void* d_out, int out_size, void* d_ws, size_t ws_size,
                              hipStream_t stream) {
    const float* x   = (const float*)d_in[0];
    const float* pal = (const float*)d_in[1];
    float* out       = (float*)d_out;

    const int threads = 256;
    const long total_threads = NPIX / PIX_PER_THREAD;          // 1,048,576
    const int blocks = (int)((total_threads + threads - 1) / threads);  // 4096

    color_reduce_kernel<<<blocks, threads, 0, stream>>>(x, pal, out);
}